// Round 10
// baseline (317.504 us; speedup 1.0000x reference)
//
#include <hip/hip_runtime.h>

// ---------------------------------------------------------------------------
// GIN 3-layer forward, bf16 split pipeline (R10):
//   prep:   convert x->bf16, hist(dst), convert W1..3 -> k-subtiled bf16
//   CSR:    scan -> bucket scatter
//   agg:    H = (1+eps)*X + gather-sum  (proven 24-VGPR kernel, row-major out)
//   gemm:   out = H @ W + b  (NO LDS: A-frags 16B from L2-hot H rows,
//           B-frags from L2-resident Wsub, bias in acc init, direct stores)
// ---------------------------------------------------------------------------

typedef __attribute__((ext_vector_type(8))) short short8;
typedef __attribute__((ext_vector_type(4))) float f32x4;

__device__ inline unsigned short f2bf(float f) {
    union { float f; unsigned u; } v; v.f = f;
    unsigned r = v.u + 0x7fffu + ((v.u >> 16) & 1u);   // RNE
    return (unsigned short)(r >> 16);
}
__device__ inline float bflo(unsigned u) { return __uint_as_float(u << 16); }
__device__ inline float bfhi(unsigned u) { return __uint_as_float(u & 0xffff0000u); }

#define ACC8(v) { acc[0]+=bflo(v.x); acc[1]+=bfhi(v.x); acc[2]+=bflo(v.y); acc[3]+=bfhi(v.y); \
                  acc[4]+=bflo(v.z); acc[5]+=bfhi(v.z); acc[6]+=bflo(v.w); acc[7]+=bfhi(v.w); }

// ---------------- prep: x->bf16, hist, W->subtiled bf16 ----------------
__global__ __launch_bounds__(256) void prep_kernel(
    const float* __restrict__ x, const int* __restrict__ dst,
    const float* __restrict__ W1, const float* __restrict__ W2,
    const float* __restrict__ W3,
    unsigned short* __restrict__ xb, int* __restrict__ cnt,
    unsigned short* __restrict__ Ws1, unsigned short* __restrict__ Ws2,
    unsigned short* __restrict__ Ws3, int M, int nE)
{
    const int i  = blockIdx.x * 256 + threadIdx.x;
    const int nx = M * 16;
    if (i < nx) {
        const float4* xf = reinterpret_cast<const float4*>(x);
        float4 a = xf[2*i], b = xf[2*i + 1];
        uint4 o;
        o.x = (unsigned)f2bf(a.x) | ((unsigned)f2bf(a.y) << 16);
        o.y = (unsigned)f2bf(a.z) | ((unsigned)f2bf(a.w) << 16);
        o.z = (unsigned)f2bf(b.x) | ((unsigned)f2bf(b.y) << 16);
        o.w = (unsigned)f2bf(b.z) | ((unsigned)f2bf(b.w) << 16);
        reinterpret_cast<uint4*>(xb)[i] = o;
    } else if (i < nx + nE) {
        atomicAdd(&cnt[dst[i - nx]], 1);
    } else {
        int j = i - nx - nE;
        const float* W; unsigned short* D;
        if (j < 32768)       { W = W1; D = Ws1; }
        else if (j < 98304)  { W = W2; D = Ws2; j -= 32768; }
        else if (j < 163840) { W = W3; D = Ws3; j -= 98304; }
        else return;
        const int k = j >> 8, n = j & 255;
        // Wsub[k/8][n][k%8] = bf16(W[k][n])
        D[((size_t)(k >> 3) * 256 + n) * 8 + (k & 7)] = f2bf(W[(size_t)k * 256 + n]);
    }
}

// ---------------- CSR scan + scatter ----------------

__global__ __launch_bounds__(1024) void scan1_kernel(
    const int* __restrict__ cnt, int* __restrict__ excl,
    int* __restrict__ bsum, int n)
{
    __shared__ int sh[1024];
    const int tid = threadIdx.x;
    const int i = blockIdx.x * 1024 + tid;
    int v = (i < n) ? cnt[i] : 0;
    sh[tid] = v;
    __syncthreads();
    #pragma unroll
    for (int off = 1; off < 1024; off <<= 1) {
        int t = (tid >= off) ? sh[tid - off] : 0;
        __syncthreads();
        sh[tid] += t;
        __syncthreads();
    }
    if (i < n) excl[i] = sh[tid] - v;
    if (tid == 1023) bsum[blockIdx.x] = sh[1023];
}

__global__ __launch_bounds__(64) void scan2_kernel(
    const int* __restrict__ bsum, int* __restrict__ boffs, int nb)
{
    __shared__ int sh[64];
    const int tid = threadIdx.x;
    int v = (tid < nb) ? bsum[tid] : 0;
    sh[tid] = v;
    __syncthreads();
    #pragma unroll
    for (int off = 1; off < 64; off <<= 1) {
        int t = (tid >= off) ? sh[tid - off] : 0;
        __syncthreads();
        sh[tid] += t;
        __syncthreads();
    }
    boffs[tid] = sh[tid] - v;  // exclusive
}

__global__ __launch_bounds__(1024) void scan3_kernel(
    const int* __restrict__ excl, const int* __restrict__ boffs,
    int* __restrict__ row_start, int* __restrict__ cursor, int n, int nE)
{
    const int i = blockIdx.x * 1024 + threadIdx.x;
    if (i < n) {
        int v = excl[i] + boffs[blockIdx.x];
        row_start[i] = v;
        cursor[i] = v;
    }
    if (i == 0) row_start[n] = nE;
}

__global__ __launch_bounds__(256) void build_adj_kernel(
    const int* __restrict__ src, const int* __restrict__ dst,
    int* __restrict__ cursor, int* __restrict__ adj, int nE)
{
    int e = blockIdx.x * 256 + threadIdx.x;
    if (e < nE) {
        int p = atomicAdd(&cursor[dst[e]], 1);
        adj[p] = src[e];
    }
}

// ---------------- aggregation (bf16 gather, fp32 acc, 16B/lane) ------------
// Proven R5 kernel: 24 VGPR, no LDS, coalesced row-major H write.

template <int C>
__global__ __launch_bounds__(256) void aggregate_bf16(
    const unsigned short* __restrict__ X, const int* __restrict__ row_start,
    const int* __restrict__ adj, const float* __restrict__ eps_arr, int layer,
    unsigned short* __restrict__ H, int M)
{
    constexpr int TPN = C / 8;        // lanes per node (16B = 8 bf16 each)
    constexpr int NPB = 256 / TPN;
    const int node = blockIdx.x * NPB + (threadIdx.x / TPN);
    const int c8   = threadIdx.x & (TPN - 1);
    if (node >= M) return;

    const uint4* __restrict__ X4 = reinterpret_cast<const uint4*>(X);

    float acc[8] = {0.f,0.f,0.f,0.f,0.f,0.f,0.f,0.f};
    const int s0 = row_start[node];
    const int s1 = row_start[node + 1];

    int j = s0;
    for (; j + 3 < s1; j += 4) {
        int a0 = adj[j], a1 = adj[j+1], a2 = adj[j+2], a3 = adj[j+3];
        uint4 v0 = X4[(size_t)a0 * TPN + c8];
        uint4 v1 = X4[(size_t)a1 * TPN + c8];
        uint4 v2 = X4[(size_t)a2 * TPN + c8];
        uint4 v3 = X4[(size_t)a3 * TPN + c8];
        ACC8(v0); ACC8(v1); ACC8(v2); ACC8(v3);
    }
    for (; j < s1; ++j) {
        uint4 v = X4[(size_t)adj[j] * TPN + c8];
        ACC8(v);
    }

    const uint4 xv = X4[(size_t)node * TPN + c8];
    const float epsv = 1.0f + eps_arr[layer];
    float o[8];
    o[0] = epsv * bflo(xv.x) + acc[0]; o[1] = epsv * bfhi(xv.x) + acc[1];
    o[2] = epsv * bflo(xv.y) + acc[2]; o[3] = epsv * bfhi(xv.y) + acc[3];
    o[4] = epsv * bflo(xv.z) + acc[4]; o[5] = epsv * bfhi(xv.z) + acc[5];
    o[6] = epsv * bflo(xv.w) + acc[6]; o[7] = epsv * bfhi(xv.w) + acc[7];

    uint4 ov;
    ov.x = (unsigned)f2bf(o[0]) | ((unsigned)f2bf(o[1]) << 16);
    ov.y = (unsigned)f2bf(o[2]) | ((unsigned)f2bf(o[3]) << 16);
    ov.z = (unsigned)f2bf(o[4]) | ((unsigned)f2bf(o[5]) << 16);
    ov.w = (unsigned)f2bf(o[6]) | ((unsigned)f2bf(o[7]) << 16);
    reinterpret_cast<uint4*>(H)[(size_t)node * TPN + c8] = ov;
}

// ---------------- GEMM, no LDS: out[M,256] = H[Mp,CIN] @ Wsub^T + b --------
// BM=32 rows/block, 4 waves split N (wave w: cols w*64..w*64+63).
// A-frag: 16B contiguous from row-major H (rows L2-hot within block).
// B-frag: 16B contiguous from k-subtiled Wsub (L2-resident).
// C stores: 16-lane contiguous segments (32B bf16 / 64B fp32).

template <int CIN, int RELU, int BF16OUT>
__global__ __launch_bounds__(256) void gemm_nolds(
    const unsigned short* __restrict__ H, const unsigned short* __restrict__ Wsub,
    const float* __restrict__ bias, void* __restrict__ out, int M)
{
    constexpr int S = CIN / 32;   // K-steps

    const int t    = threadIdx.x;
    const int bm   = blockIdx.x * 32;
    const int w    = t >> 6, lane = t & 63;
    const int lr   = lane & 15, ko = lane >> 4;

    f32x4 acc[2][4];
    #pragma unroll
    for (int fn = 0; fn < 4; ++fn) {
        const float bb = bias[w*64 + fn*16 + lr];
        #pragma unroll
        for (int fm = 0; fm < 2; ++fm) {
            acc[fm][fn][0] = bb; acc[fm][fn][1] = bb;
            acc[fm][fn][2] = bb; acc[fm][fn][3] = bb;
        }
    }

    #pragma unroll
    for (int s = 0; s < S; ++s) {
        short8 af[2], bf8[4];
        #pragma unroll
        for (int fm = 0; fm < 2; ++fm)
            af[fm] = *reinterpret_cast<const short8*>(
                H + (size_t)(bm + fm*16 + lr) * CIN + s*32 + ko*8);
        #pragma unroll
        for (int fn = 0; fn < 4; ++fn)
            bf8[fn] = *reinterpret_cast<const short8*>(
                Wsub + ((size_t)(s*4 + ko) * 256 + w*64 + fn*16 + lr) * 8);
        #pragma unroll
        for (int fm = 0; fm < 2; ++fm)
            #pragma unroll
            for (int fn = 0; fn < 4; ++fn)
                acc[fm][fn] = __builtin_amdgcn_mfma_f32_16x16x32_bf16(
                    af[fm], bf8[fn], acc[fm][fn], 0, 0, 0);
    }

    // C/D layout: col = lane&15, row = (lane>>4)*4 + r
    #pragma unroll
    for (int fm = 0; fm < 2; ++fm) {
        #pragma unroll
        for (int fn = 0; fn < 4; ++fn) {
            const int col = w*64 + fn*16 + lr;
            #pragma unroll
            for (int r = 0; r < 4; ++r) {
                const int row = bm + fm*16 + ko*4 + r;
                if (row < M) {
                    float v = acc[fm][fn][r];
                    if (RELU) v = fmaxf(v, 0.f);
                    if (BF16OUT)
                        ((unsigned short*)out)[(size_t)row * 256 + col] = f2bf(v);
                    else
                        ((float*)out)[(size_t)row * 256 + col] = v;
                }
            }
        }
    }
}

// ---------------- launch ----------------

extern "C" void kernel_launch(void* const* d_in, const int* in_sizes, int n_in,
                              void* d_out, int out_size, void* d_ws, size_t ws_size,
                              hipStream_t stream)
{
    const float* x   = (const float*)d_in[0];
    const int*   ei  = (const int*)  d_in[1];
    const float* W1  = (const float*)d_in[2];
    const float* b1  = (const float*)d_in[3];
    const float* W2  = (const float*)d_in[4];
    const float* b2  = (const float*)d_in[5];
    const float* W3  = (const float*)d_in[6];
    const float* b3  = (const float*)d_in[7];
    const float* eps = (const float*)d_in[8];

    const int M  = in_sizes[0] / 128;   // 50000
    const int nE = in_sizes[1] / 2;     // 800000
    const int Mp = ((M + 31) / 32) * 32;   // pad rows for GEMM A reads
    const int* srcI = ei;
    const int* dstI = ei + nE;

    // workspace layout
    char* p = (char*)d_ws;
    unsigned short* xb  = (unsigned short*)p; p += (size_t)Mp * 128 * 2;
    unsigned short* h1  = (unsigned short*)p; p += (size_t)Mp * 256 * 2;
    unsigned short* h2  = (unsigned short*)p; p += (size_t)Mp * 256 * 2;
    unsigned short* Ws1 = (unsigned short*)p; p += (size_t)128 * 256 * 2;
    unsigned short* Ws2 = (unsigned short*)p; p += (size_t)256 * 256 * 2;
    unsigned short* Ws3 = (unsigned short*)p; p += (size_t)256 * 256 * 2;
    int* cnt       = (int*)p; p += (size_t)M * 4;
    int* excl      = (int*)p; p += (size_t)M * 4;
    int* bsum      = (int*)p; p += 64 * 4;
    int* boffs     = (int*)p; p += 64 * 4;
    int* row_start = (int*)p; p += (size_t)(M + 2) * 4;
    int* cursor    = (int*)p; p += (size_t)M * 4;
    int* adj       = (int*)p; p += (size_t)nE * 4;

    const int nbl = (M + 1023) / 1024;   // 49

    hipMemsetAsync(cnt, 0, (size_t)M * sizeof(int), stream);
    {
        const int total = M * 16 + nE + 163840;
        prep_kernel<<<(total + 255) / 256, 256, 0, stream>>>(
            x, dstI, W1, W2, W3, xb, cnt, Ws1, Ws2, Ws3, M, nE);
    }
    scan1_kernel<<<nbl, 1024, 0, stream>>>(cnt, excl, bsum, M);
    scan2_kernel<<<1, 64, 0, stream>>>(bsum, boffs, nbl);
    scan3_kernel<<<nbl, 1024, 0, stream>>>(excl, boffs, row_start, cursor, M, nE);
    build_adj_kernel<<<(nE + 255) / 256, 256, 0, stream>>>(srcI, dstI, cursor, adj, nE);

    const int gblk = Mp / 32;   // 1563

    // layer 1 (CIN=128)
    aggregate_bf16<128><<<(M + 15) / 16, 256, 0, stream>>>(
        xb, row_start, adj, eps, 0, h1, M);
    gemm_nolds<128, 1, 1><<<gblk, 256, 0, stream>>>(h1, Ws1, b1, h2, M);

    // layer 2 (CIN=256)  (h2 holds layer-1 output)
    aggregate_bf16<256><<<(M + 7) / 8, 256, 0, stream>>>(
        h2, row_start, adj, eps, 1, h1, M);
    gemm_nolds<256, 1, 1><<<gblk, 256, 0, stream>>>(h1, Ws2, b2, h2, M);

    // layer 3 (CIN=256, no relu, fp32 out)
    aggregate_bf16<256><<<(M + 7) / 8, 256, 0, stream>>>(
        h2, row_start, adj, eps, 2, h1, M);
    gemm_nolds<256, 0, 0><<<gblk, 256, 0, stream>>>(h1, Ws3, b3, d_out, M);
}

// Round 11
// 301.774 us; speedup vs baseline: 1.0521x; 1.0521x over previous
//
#include <hip/hip_runtime.h>

// ---------------------------------------------------------------------------
// GIN 3-layer forward, bf16 split pipeline (R11):
//   prep:   convert x->bf16, hist(dst), convert W1..3 -> k-subtiled bf16
//   CSR:    scan1 -> scan3 (self-scanning block offsets) -> bucket scatter
//   agg:    H = (1+eps)*X + gather-sum  (proven 24-VGPR kernel)
//   gemm:   BM=64 tile: A via global_load_lds into k-subtiled LDS (linear dest,
//           permuted per-lane src), B-frags direct from L2-resident Wsub,
//           16 MFMA/wave/K-step, bias in acc init, direct stores.
// ---------------------------------------------------------------------------

typedef __attribute__((ext_vector_type(8))) short short8;
typedef __attribute__((ext_vector_type(4))) float f32x4;

__device__ inline unsigned short f2bf(float f) {
    union { float f; unsigned u; } v; v.f = f;
    unsigned r = v.u + 0x7fffu + ((v.u >> 16) & 1u);   // RNE
    return (unsigned short)(r >> 16);
}
__device__ inline float bflo(unsigned u) { return __uint_as_float(u << 16); }
__device__ inline float bfhi(unsigned u) { return __uint_as_float(u & 0xffff0000u); }

__device__ __forceinline__ void gload_lds16(const unsigned short* g, unsigned short* l) {
    __builtin_amdgcn_global_load_lds(
        (const __attribute__((address_space(1))) unsigned int*)g,
        (__attribute__((address_space(3))) unsigned int*)l,
        16, 0, 0);
}

#define ACC8(v) { acc[0]+=bflo(v.x); acc[1]+=bfhi(v.x); acc[2]+=bflo(v.y); acc[3]+=bfhi(v.y); \
                  acc[4]+=bflo(v.z); acc[5]+=bfhi(v.z); acc[6]+=bflo(v.w); acc[7]+=bfhi(v.w); }

// ---------------- prep: x->bf16, hist, W->subtiled bf16 ----------------
__global__ __launch_bounds__(256) void prep_kernel(
    const float* __restrict__ x, const int* __restrict__ dst,
    const float* __restrict__ W1, const float* __restrict__ W2,
    const float* __restrict__ W3,
    unsigned short* __restrict__ xb, int* __restrict__ cnt,
    unsigned short* __restrict__ Ws1, unsigned short* __restrict__ Ws2,
    unsigned short* __restrict__ Ws3, int M, int nE)
{
    const int i  = blockIdx.x * 256 + threadIdx.x;
    const int nx = M * 16;
    if (i < nx) {
        const float4* xf = reinterpret_cast<const float4*>(x);
        float4 a = xf[2*i], b = xf[2*i + 1];
        uint4 o;
        o.x = (unsigned)f2bf(a.x) | ((unsigned)f2bf(a.y) << 16);
        o.y = (unsigned)f2bf(a.z) | ((unsigned)f2bf(a.w) << 16);
        o.z = (unsigned)f2bf(b.x) | ((unsigned)f2bf(b.y) << 16);
        o.w = (unsigned)f2bf(b.z) | ((unsigned)f2bf(b.w) << 16);
        reinterpret_cast<uint4*>(xb)[i] = o;
    } else if (i < nx + nE) {
        atomicAdd(&cnt[dst[i - nx]], 1);
    } else {
        int j = i - nx - nE;
        const float* W; unsigned short* D;
        if (j < 32768)       { W = W1; D = Ws1; }
        else if (j < 98304)  { W = W2; D = Ws2; j -= 32768; }
        else if (j < 163840) { W = W3; D = Ws3; j -= 98304; }
        else return;
        const int k = j >> 8, n = j & 255;
        // Wsub[k/8][n][k%8] = bf16(W[k][n])
        D[((size_t)(k >> 3) * 256 + n) * 8 + (k & 7)] = f2bf(W[(size_t)k * 256 + n]);
    }
}

// ---------------- CSR scan + scatter ----------------

__global__ __launch_bounds__(1024) void scan1_kernel(
    const int* __restrict__ cnt, int* __restrict__ excl,
    int* __restrict__ bsum, int n)
{
    __shared__ int sh[1024];
    const int tid = threadIdx.x;
    const int i = blockIdx.x * 1024 + tid;
    int v = (i < n) ? cnt[i] : 0;
    sh[tid] = v;
    __syncthreads();
    #pragma unroll
    for (int off = 1; off < 1024; off <<= 1) {
        int t = (tid >= off) ? sh[tid - off] : 0;
        __syncthreads();
        sh[tid] += t;
        __syncthreads();
    }
    if (i < n) excl[i] = sh[tid] - v;
    if (tid == 1023) bsum[blockIdx.x] = sh[1023];
}

// scan3: each block scans bsum[0..nbl) itself (nbl <= 64), adds to excl.
__global__ __launch_bounds__(1024) void scan3_kernel(
    const int* __restrict__ excl, const int* __restrict__ bsum,
    int* __restrict__ row_start, int* __restrict__ cursor,
    int n, int nE, int nbl)
{
    __shared__ int sb[64];
    const int tid = threadIdx.x;
    if (tid < 64) sb[tid] = (tid < nbl) ? bsum[tid] : 0;
    __syncthreads();
    #pragma unroll
    for (int off = 1; off < 64; off <<= 1) {
        int v = 0;
        if (tid < 64 && tid >= off) v = sb[tid - off];
        __syncthreads();
        if (tid < 64) sb[tid] += v;
        __syncthreads();
    }
    const int boff = sb[blockIdx.x] - bsum[blockIdx.x];   // exclusive offset
    const int i = blockIdx.x * 1024 + tid;
    if (i < n) {
        int v = excl[i] + boff;
        row_start[i] = v;
        cursor[i] = v;
    }
    if (i == 0) row_start[n] = nE;
}

__global__ __launch_bounds__(256) void build_adj_kernel(
    const int* __restrict__ src, const int* __restrict__ dst,
    int* __restrict__ cursor, int* __restrict__ adj, int nE)
{
    int e = blockIdx.x * 256 + threadIdx.x;
    if (e < nE) {
        int p = atomicAdd(&cursor[dst[e]], 1);
        adj[p] = src[e];
    }
}

// ---------------- aggregation (bf16 gather, fp32 acc, 16B/lane) ------------

template <int C>
__global__ __launch_bounds__(256) void aggregate_bf16(
    const unsigned short* __restrict__ X, const int* __restrict__ row_start,
    const int* __restrict__ adj, const float* __restrict__ eps_arr, int layer,
    unsigned short* __restrict__ H, int M)
{
    constexpr int TPN = C / 8;        // lanes per node (16B = 8 bf16 each)
    constexpr int NPB = 256 / TPN;
    const int node = blockIdx.x * NPB + (threadIdx.x / TPN);
    const int c8   = threadIdx.x & (TPN - 1);
    if (node >= M) return;

    const uint4* __restrict__ X4 = reinterpret_cast<const uint4*>(X);

    float acc[8] = {0.f,0.f,0.f,0.f,0.f,0.f,0.f,0.f};
    const int s0 = row_start[node];
    const int s1 = row_start[node + 1];

    int j = s0;
    for (; j + 3 < s1; j += 4) {
        int a0 = adj[j], a1 = adj[j+1], a2 = adj[j+2], a3 = adj[j+3];
        uint4 v0 = X4[(size_t)a0 * TPN + c8];
        uint4 v1 = X4[(size_t)a1 * TPN + c8];
        uint4 v2 = X4[(size_t)a2 * TPN + c8];
        uint4 v3 = X4[(size_t)a3 * TPN + c8];
        ACC8(v0); ACC8(v1); ACC8(v2); ACC8(v3);
    }
    for (; j < s1; ++j) {
        uint4 v = X4[(size_t)adj[j] * TPN + c8];
        ACC8(v);
    }

    const uint4 xv = X4[(size_t)node * TPN + c8];
    const float epsv = 1.0f + eps_arr[layer];
    float o[8];
    o[0] = epsv * bflo(xv.x) + acc[0]; o[1] = epsv * bfhi(xv.x) + acc[1];
    o[2] = epsv * bflo(xv.y) + acc[2]; o[3] = epsv * bfhi(xv.y) + acc[3];
    o[4] = epsv * bflo(xv.z) + acc[4]; o[5] = epsv * bfhi(xv.z) + acc[5];
    o[6] = epsv * bflo(xv.w) + acc[6]; o[7] = epsv * bfhi(xv.w) + acc[7];

    uint4 ov;
    ov.x = (unsigned)f2bf(o[0]) | ((unsigned)f2bf(o[1]) << 16);
    ov.y = (unsigned)f2bf(o[2]) | ((unsigned)f2bf(o[3]) << 16);
    ov.z = (unsigned)f2bf(o[4]) | ((unsigned)f2bf(o[5]) << 16);
    ov.w = (unsigned)f2bf(o[6]) | ((unsigned)f2bf(o[7]) << 16);
    reinterpret_cast<uint4*>(H)[(size_t)node * TPN + c8] = ov;
}

// ---------------- GEMM: BM=64, A via gload_lds (k-subtiled), B from L2 -----
// As[kb][row][8]: LDS-linear unit index = t; global src permuted per lane:
//   thread t stages H[bm + (t&63)][k0 + (t>>6)*8 .. +8)  -> one gload_lds16.
// A-frag read As[ko][fm*16+lr]: 16 lanes consecutive 16B units, conflict-free.
// Wave w covers cols w*64..w*64+63 (4 fn frags). 16 MFMA / wave / K-step.

template <int CIN, int RELU, int BF16OUT>
__global__ __launch_bounds__(256) void gemm_tiled(
    const unsigned short* __restrict__ H, const unsigned short* __restrict__ Wsub,
    const float* __restrict__ bias, void* __restrict__ out, int M)
{
    constexpr int S = CIN / 32;   // K-steps

    __shared__ __align__(16) unsigned short As[4][64][8];   // 4 KB

    const int t    = threadIdx.x;
    const int bm   = blockIdx.x * 64;
    const int w    = t >> 6, lane = t & 63;
    const int lr   = lane & 15, ko = lane >> 4;

    const int srow = t & 63;
    const unsigned short* aG = H + (size_t)(bm + srow) * CIN + (t >> 6) * 8;
    unsigned short* lA = &As[t >> 6][srow][0];

    f32x4 acc[4][4];
    #pragma unroll
    for (int fn = 0; fn < 4; ++fn) {
        const float bb = bias[w*64 + fn*16 + lr];
        #pragma unroll
        for (int fm = 0; fm < 4; ++fm) {
            acc[fm][fn][0] = bb; acc[fm][fn][1] = bb;
            acc[fm][fn][2] = bb; acc[fm][fn][3] = bb;
        }
    }

    for (int s = 0; s < S; ++s) {
        gload_lds16(aG + s*32, lA);
        __syncthreads();

        short8 af[4], bf8[4];
        #pragma unroll
        for (int fm = 0; fm < 4; ++fm)
            af[fm] = *reinterpret_cast<const short8*>(&As[ko][fm*16 + lr][0]);
        #pragma unroll
        for (int fn = 0; fn < 4; ++fn)
            bf8[fn] = *reinterpret_cast<const short8*>(
                Wsub + ((size_t)(s*4 + ko) * 256 + w*64 + fn*16 + lr) * 8);
        #pragma unroll
        for (int fm = 0; fm < 4; ++fm)
            #pragma unroll
            for (int fn = 0; fn < 4; ++fn)
                acc[fm][fn] = __builtin_amdgcn_mfma_f32_16x16x32_bf16(
                    af[fm], bf8[fn], acc[fm][fn], 0, 0, 0);

        __syncthreads();
    }

    // C/D layout: col = lane&15, row = (lane>>4)*4 + r
    #pragma unroll
    for (int fm = 0; fm < 4; ++fm) {
        #pragma unroll
        for (int fn = 0; fn < 4; ++fn) {
            const int col = w*64 + fn*16 + lr;
            #pragma unroll
            for (int r = 0; r < 4; ++r) {
                const int row = bm + fm*16 + ko*4 + r;
                if (row < M) {
                    float v = acc[fm][fn][r];
                    if (RELU) v = fmaxf(v, 0.f);
                    if (BF16OUT)
                        ((unsigned short*)out)[(size_t)row * 256 + col] = f2bf(v);
                    else
                        ((float*)out)[(size_t)row * 256 + col] = v;
                }
            }
        }
    }
}

// ---------------- launch ----------------

extern "C" void kernel_launch(void* const* d_in, const int* in_sizes, int n_in,
                              void* d_out, int out_size, void* d_ws, size_t ws_size,
                              hipStream_t stream)
{
    const float* x   = (const float*)d_in[0];
    const int*   ei  = (const int*)  d_in[1];
    const float* W1  = (const float*)d_in[2];
    const float* b1  = (const float*)d_in[3];
    const float* W2  = (const float*)d_in[4];
    const float* b2  = (const float*)d_in[5];
    const float* W3  = (const float*)d_in[6];
    const float* b3  = (const float*)d_in[7];
    const float* eps = (const float*)d_in[8];

    const int M  = in_sizes[0] / 128;   // 50000
    const int nE = in_sizes[1] / 2;     // 800000
    const int Mp = ((M + 63) / 64) * 64;   // pad rows for GEMM tiles
    const int* srcI = ei;
    const int* dstI = ei + nE;

    // workspace layout
    char* p = (char*)d_ws;
    unsigned short* xb  = (unsigned short*)p; p += (size_t)Mp * 128 * 2;
    unsigned short* h1  = (unsigned short*)p; p += (size_t)Mp * 256 * 2;
    unsigned short* h2  = (unsigned short*)p; p += (size_t)Mp * 256 * 2;
    unsigned short* Ws1 = (unsigned short*)p; p += (size_t)128 * 256 * 2;
    unsigned short* Ws2 = (unsigned short*)p; p += (size_t)256 * 256 * 2;
    unsigned short* Ws3 = (unsigned short*)p; p += (size_t)256 * 256 * 2;
    int* cnt       = (int*)p; p += (size_t)M * 4;
    int* excl      = (int*)p; p += (size_t)M * 4;
    int* bsum      = (int*)p; p += 64 * 4;
    int* row_start = (int*)p; p += (size_t)(M + 2) * 4;
    int* cursor    = (int*)p; p += (size_t)M * 4;
    int* adj       = (int*)p; p += (size_t)nE * 4;

    const int nbl = (M + 1023) / 1024;   // 49

    hipMemsetAsync(cnt, 0, (size_t)M * sizeof(int), stream);
    {
        const int total = M * 16 + nE + 163840;
        prep_kernel<<<(total + 255) / 256, 256, 0, stream>>>(
            x, dstI, W1, W2, W3, xb, cnt, Ws1, Ws2, Ws3, M, nE);
    }
    scan1_kernel<<<nbl, 1024, 0, stream>>>(cnt, excl, bsum, M);
    scan3_kernel<<<nbl, 1024, 0, stream>>>(excl, bsum, row_start, cursor, M, nE, nbl);
    build_adj_kernel<<<(nE + 255) / 256, 256, 0, stream>>>(srcI, dstI, cursor, adj, nE);

    const int gblk = Mp / 64;   // 782

    // layer 1 (CIN=128)
    aggregate_bf16<128><<<(M + 15) / 16, 256, 0, stream>>>(
        xb, row_start, adj, eps, 0, h1, M);
    gemm_tiled<128, 1, 1><<<gblk, 256, 0, stream>>>(h1, Ws1, b1, h2, M);

    // layer 2 (CIN=256)
    aggregate_bf16<256><<<(M + 7) / 8, 256, 0, stream>>>(
        h2, row_start, adj, eps, 1, h1, M);
    gemm_tiled<256, 1, 1><<<gblk, 256, 0, stream>>>(h1, Ws2, b2, h2, M);

    // layer 3 (CIN=256, no relu, fp32 out)
    aggregate_bf16<256><<<(M + 7) / 8, 256, 0, stream>>>(
        h2, row_start, adj, eps, 2, h1, M);
    gemm_tiled<256, 0, 0><<<gblk, 256, 0, stream>>>(h1, Ws3, b3, d_out, M);
}